// Round 3
// baseline (228.179 us; speedup 1.0000x reference)
//
#include <hip/hip_runtime.h>

// 3x3 'SAME' conv per independent 4x4 tile, masked to nonzero input sites.
// x flat [N,4,4]; output [N,1,4,4] is flat-identical (C=1).
//
// R1 structure (one thread per float4 row, vertical taps via intra-wave
// shuffles) + R2 change: 4 rows per thread with all 4 global loads issued
// up-front -> 4x memory-level parallelism per wave, 4x amortization of
// weight loads / addressing. Rows per block: 4*256 = 1024 consecutive.

#define ROWS_PER_THREAD 4

__global__ __launch_bounds__(256) void subm_conv44_row4_kernel(
    const float4* __restrict__ x4, const float* __restrict__ W,
    float4* __restrict__ out4, int n_rows)
{
    const int base = blockIdx.x * (256 * ROWS_PER_THREAD) + threadIdx.x;

    // 3x3 weight, w[ki*3+kj] (HWIO with I=O=1 is flat row-major 3x3).
    float w[9];
#pragma unroll
    for (int i = 0; i < 9; ++i) w[i] = W[i];   // uniform -> scalar/broadcast

    // Issue all 4 independent coalesced loads before any use.
    float4 c[ROWS_PER_THREAD];
    int idx[ROWS_PER_THREAD];
    bool ok[ROWS_PER_THREAD];
#pragma unroll
    for (int k = 0; k < ROWS_PER_THREAD; ++k) {
        idx[k] = base + k * 256;               // lanes consecutive per iter
        ok[k] = (idx[k] < n_rows);
        c[k] = ok[k] ? x4[idx[k]] : make_float4(0.f, 0.f, 0.f, 0.f);
    }

#pragma unroll
    for (int k = 0; k < ROWS_PER_THREAD; ++k) {
        // Row r of tile idx[k]>>2. idx[k] % 4 == threadIdx.x % 4 (all other
        // addends are multiples of 4), so a tile is 4 consecutive lanes and
        // never straddles a wave.
        const int r = idx[k] & 3;

        float4 u, d;
        u.x = __shfl_up(c[k].x, 1);   u.y = __shfl_up(c[k].y, 1);
        u.z = __shfl_up(c[k].z, 1);   u.w = __shfl_up(c[k].w, 1);
        d.x = __shfl_down(c[k].x, 1); d.y = __shfl_down(c[k].y, 1);
        d.z = __shfl_down(c[k].z, 1); d.w = __shfl_down(c[k].w, 1);

        const bool hasU = (r > 0);
        const bool hasD = (r < 3);

        // Zero-padded horizontal windows: idx 0 and 5 are pad columns.
        float up[6] = {0.f, hasU ? u.x : 0.f, hasU ? u.y : 0.f,
                            hasU ? u.z : 0.f, hasU ? u.w : 0.f, 0.f};
        float mi[6] = {0.f, c[k].x, c[k].y, c[k].z, c[k].w, 0.f};
        float dn[6] = {0.f, hasD ? d.x : 0.f, hasD ? d.y : 0.f,
                            hasD ? d.z : 0.f, hasD ? d.w : 0.f, 0.f};

        float4 o;
        float* op = &o.x;
#pragma unroll
        for (int j = 0; j < 4; ++j) {
            float acc = 0.0f;
#pragma unroll
            for (int t = 0; t < 3; ++t) {
                acc = fmaf(up[j + t], w[0 * 3 + t], acc);
                acc = fmaf(mi[j + t], w[1 * 3 + t], acc);
                acc = fmaf(dn[j + t], w[2 * 3 + t], acc);
            }
            // Submanifold mask: write only where the input site was nonzero.
            op[j] = (mi[j + 1] != 0.0f) ? acc : 0.0f;
        }

        if (ok[k]) out4[idx[k]] = o;           // coalesced store
    }
}

extern "C" void kernel_launch(void* const* d_in, const int* in_sizes, int n_in,
                              void* d_out, int out_size, void* d_ws, size_t ws_size,
                              hipStream_t stream) {
    const float4* x4 = (const float4*)d_in[0];
    const float*  W  = (const float*)d_in[1];
    float4* out4     = (float4*)d_out;

    const int n_rows = in_sizes[0] / 4;                    // 8,388,608
    const int rows_per_block = 256 * ROWS_PER_THREAD;      // 1024
    const int grid = (n_rows + rows_per_block - 1) / rows_per_block;  // 8192

    subm_conv44_row4_kernel<<<grid, 256, 0, stream>>>(x4, W, out4, n_rows);
}